// Round 16
// baseline (23.545 us; speedup 1.0000x reference)
//
#include <hip/hip_runtime.h>

typedef short bf16x8 __attribute__((ext_vector_type(8)));
typedef float f32x4  __attribute__((ext_vector_type(4)));
typedef unsigned int u32;

#define HH 128
#define WW 128

__device__ __forceinline__ u32 cvt_pk_bf16(float lo, float hi) {
    u32 r;
    asm volatile("v_cvt_pk_bf16_f32 %0, %1, %2" : "=v"(r) : "v"(lo), "v"(hi));
    return r;   // low16 = bf16(lo), high16 = bf16(hi)
}

// LDS-only barrier (does not drain global loads/stores).
__device__ __forceinline__ void lds_barrier() {
    asm volatile("s_waitcnt lgkmcnt(0)" ::: "memory");
    __builtin_amdgcn_s_barrier();
    __builtin_amdgcn_sched_barrier(0);
}

// Implicit-GEMM conv via 9 shifted 32x32 channel GEMMs on mfma_f32_16x16x32_bf16.
// Block: 1024 thr (16 waves) owns 8 contiguous output rows of one batch.
// ISSUE ORDER (vmcnt is in-order!): tiny loads (codes/bias/bctx) ->
// weight-synth inputs (weight/A/Bm, registers) -> x rows 0..5 -> [synth+cvt,
// waiting only on early loads] -> issue x rows 6..9 -> barrier -> chunk0
// compute -> cvt rows 6..9 -> chunk0 coalesced epilogue (bounce slots 0..3)
// -> chunk1 compute (no barrier; stores drain underneath) -> chunk1 epilogue.
// Wave = (row4 0..3, nq 0..3): 1 row, 2 col-tiles, all 32 out-ch
// (A-frag oh=0 resident, oh=1 re-read from LDS in-loop).
// Grid: 256 blocks (16 b x 16 groups), XCD-bijective swizzle, 1 block/CU.
__global__ __launch_bounds__(1024, 1) void geps_mfma_kernel(
    const float* __restrict__ x, const float* __restrict__ codes,
    const float* __restrict__ weight, const float* __restrict__ A,
    const float* __restrict__ Bm, const float* __restrict__ bias,
    const float* __restrict__ bctx, float* __restrict__ out)
{
    __shared__ bf16x8 lds_x[5120];    // [10 slots][512 entries] = 80 KB (+ bounce)
    __shared__ bf16x8 lds_w[1152];    // [9 kl][2 oh][4 kb][16 o] x 8i bf16
    __shared__ float  lds_b[32];

    const int tid  = threadIdx.x;
    const int l    = tid & 63;
    const int wvid = tid >> 6;         // 0..15
    const int row4 = wvid >> 2;        // 0..3 (row within 4-row chunk)
    const int nq   = wvid & 3;         // 0..3 (col-tiles nq*2, nq*2+1)

    // XCD-aware bijective swizzle: 256 blocks = 8 XCDs x 32 contiguous.
    const int orig = blockIdx.x;
    const int vb   = (orig & 7) * 32 + (orig >> 3);
    const int b    = vb >> 4;          // batch 0..15
    const int grp  = vb & 15;          // 8-row group 0..15
    const int h0   = grp * 8;

    // ---- Tiny loads first (clear vmcnt early) ----
    const float c00 = codes[b * 4 + 0];
    const float c01 = codes[b * 4 + 1];
    const float c10 = codes[b * 4 + 2];
    const float c11 = codes[b * 4 + 3];
    float bv = 0.f, bx0 = 0.f, bx1 = 0.f;
    if (tid < 32) { bv = bias[tid]; bx0 = bctx[tid]; bx1 = bctx[32 + tid]; }

    // ---- Weight-synth input prefetch (registers; before the x burst) ----
    // item0: j = tid (always valid, 1024 < 1152); item1: j = tid+1024 (tid<128).
    const int j0 = tid, j1 = tid + 1024;
    const int kl0 = j0 >> 7, o0 = (j0 & 127) >> 2, kb0 = j0 & 3;
    float m0a, m1a, wga[8], a0a[8], a1a[8];
    m0a = Bm[(o0 * 2 + 0) * 9 + kl0];
    m1a = Bm[(o0 * 2 + 1) * 9 + kl0];
    #pragma unroll
    for (int jj = 0; jj < 8; ++jj) {
        int i = kb0 * 8 + jj;
        wga[jj] = weight[(o0 * 32 + i) * 9 + kl0];
        a0a[jj] = A[(i * 2 + 0) * 9 + kl0];
        a1a[jj] = A[(i * 2 + 1) * 9 + kl0];
    }
    const int kl1 = j1 >> 7, o1 = (j1 & 127) >> 2, kb1 = j1 & 3;
    float m0b = 0, m1b = 0, wgb[8], a0b[8], a1b[8];
    if (tid < 128) {
        m0b = Bm[(o1 * 2 + 0) * 9 + kl1];
        m1b = Bm[(o1 * 2 + 1) * 9 + kl1];
        #pragma unroll
        for (int jj = 0; jj < 8; ++jj) {
            int i = kb1 * 8 + jj;
            wgb[jj] = weight[(o1 * 32 + i) * 9 + kl1];
            a0b[jj] = A[(i * 2 + 0) * 9 + kl1];
            a1b[jj] = A[(i * 2 + 1) * 9 + kl1];
        }
    }

    // ---- Issue x loads rows h0-1..h0+4 (-> slots 0..5) ----
    float2 f[3][4];
    #pragma unroll
    for (int it = 0; it < 3; ++it) {
        int idx = it * 1024 + tid;     // < 3072
        int cp = idx & 63, jh = (idx >> 6) & 1, ig = (idx >> 7) & 3, rr = idx >> 9;
        int grow = (h0 - 1 + rr) & 127;
        const float* src =
            x + ((size_t)(b * 32 + ig * 8 + jh * 4) * HH + grow) * WW + cp * 2;
        #pragma unroll
        for (int jj = 0; jj < 4; ++jj)
            f[it][jj] = *(const float2*)(src + (size_t)jj * HH * WW);
    }

    // ---- Weight synthesis (register-fed; waits only on early loads) ----
    {
        float wf[8];
        #pragma unroll
        for (int jj = 0; jj < 8; ++jj) {
            float t0 = a0a[jj] * c00 + a1a[jj] * c10;
            float t1 = a0a[jj] * c01 + a1a[jj] * c11;
            wf[jj] = wga[jj] + t0 * m0a + t1 * m1a;
        }
        u32 pk[4];
        #pragma unroll
        for (int q = 0; q < 4; ++q) pk[q] = cvt_pk_bf16(wf[2 * q], wf[2 * q + 1]);
        *(uint4*)&lds_w[kl0 * 128 + (o0 >> 4) * 64 + kb0 * 16 + (o0 & 15)] =
            make_uint4(pk[0], pk[1], pk[2], pk[3]);
    }
    if (tid < 128) {
        float wf[8];
        #pragma unroll
        for (int jj = 0; jj < 8; ++jj) {
            float t0 = a0b[jj] * c00 + a1b[jj] * c10;
            float t1 = a0b[jj] * c01 + a1b[jj] * c11;
            wf[jj] = wgb[jj] + t0 * m0b + t1 * m1b;
        }
        u32 pk[4];
        #pragma unroll
        for (int q = 0; q < 4; ++q) pk[q] = cvt_pk_bf16(wf[2 * q], wf[2 * q + 1]);
        *(uint4*)&lds_w[kl1 * 128 + (o1 >> 4) * 64 + kb1 * 16 + (o1 & 15)] =
            make_uint4(pk[0], pk[1], pk[2], pk[3]);
    }
    if (tid < 32) lds_b[tid] = bv + c00 * bx0 + c11 * bx1;

    // ---- Convert + write rows 0..5 to slots 0..5 ----
    #pragma unroll
    for (int it = 0; it < 3; ++it) {
        int idx = it * 1024 + tid;
        int cp = idx & 63, jh = (idx >> 6) & 1, ig = (idx >> 7) & 3, rr = idx >> 9;
        int c0 = cp * 2;
        u32 a0 = cvt_pk_bf16(f[it][0].x, f[it][1].x);
        u32 a1 = cvt_pk_bf16(f[it][2].x, f[it][3].x);
        u32 b0 = cvt_pk_bf16(f[it][0].y, f[it][1].y);
        u32 b1 = cvt_pk_bf16(f[it][2].y, f[it][3].y);
        int didx = (c0 >> 4) * 64 + ig * 16 + (c0 & 15);
        *(uint2*)((char*)lds_x + rr * 8192 + didx * 16 + jh * 8) =
            make_uint2(a0, a1);
        *(uint2*)((char*)lds_x + rr * 8192 + (didx + 1) * 16 + jh * 8) =
            make_uint2(b0, b1);
    }

    // ---- Issue deferred x loads rows h0+5..h0+8 (-> slots 6..9 later) ----
    float2 fd[2][4];
    #pragma unroll
    for (int it = 0; it < 2; ++it) {
        int idx = it * 1024 + tid;     // < 2048
        int cp = idx & 63, jh = (idx >> 6) & 1, ig = (idx >> 7) & 3;
        int rr = 6 + (idx >> 9);       // 6..9
        int grow = (h0 - 1 + rr) & 127;
        const float* src =
            x + ((size_t)(b * 32 + ig * 8 + jh * 4) * HH + grow) * WW + cp * 2;
        #pragma unroll
        for (int jj = 0; jj < 4; ++jj)
            fd[it][jj] = *(const float2*)(src + (size_t)jj * HH * WW);
    }

    lds_barrier();   // slots 0..5 + lds_w + lds_b ready

    // ---- A fragments: oh=0 resident; oh=1 re-read in-loop ----
    const int awb = (l >> 4) * 16 + (l & 15);
    bf16x8 af0[9];
    #pragma unroll
    for (int kl = 0; kl < 9; ++kl)
        af0[kl] = lds_w[kl * 128 + awb];

    const int p = l & 15, igf = l >> 4;
    int bb[3];
    #pragma unroll
    for (int dl = -1; dl <= 1; ++dl) {
        int pq = p + dl;                       // -1..16
        bb[dl + 1] = (pq & 15) + ((pq >> 4) << 6) + igf * 16;  // 16B-elem units
    }

    float blr[2][4];
    #pragma unroll
    for (int oh = 0; oh < 2; ++oh)
        #pragma unroll
        for (int r = 0; r < 4; ++r)
            blr[oh][r] = lds_b[oh * 16 + (l >> 4) * 4 + r];

    // ================== Chunk 0: rows h0+row4, slots row4..row4+2 ==========
    f32x4 acc[2][2];
    #pragma unroll
    for (int oh = 0; oh < 2; ++oh)
        #pragma unroll
        for (int q = 0; q < 2; ++q) acc[oh][q] = (f32x4){0.f, 0.f, 0.f, 0.f};

    #pragma unroll
    for (int lc = 0; lc < 3; ++lc) {
        #pragma unroll
        for (int k = 0; k < 3; ++k) {
            const bf16x8 a0 = af0[k * 3 + lc];
            const bf16x8 a1 = lds_w[(k * 3 + lc) * 128 + 64 + awb];
            const int s = row4 + k;
            #pragma unroll
            for (int q = 0; q < 2; ++q) {
                int t = (bb[lc] + (nq * 2 + q) * 64) & 511;  // col wrap
                bf16x8 bfv = lds_x[s * 512 + t];
                acc[0][q] = __builtin_amdgcn_mfma_f32_16x16x32_bf16(
                    a0, bfv, acc[0][q], 0, 0, 0);
                acc[1][q] = __builtin_amdgcn_mfma_f32_16x16x32_bf16(
                    a1, bfv, acc[1][q], 0, 0, 0);
            }
        }
    }

    // ---- Deferred cvt rows 6..9 -> slots 6..9 (disjoint from chunk0 reads) ----
    #pragma unroll
    for (int it = 0; it < 2; ++it) {
        int idx = it * 1024 + tid;
        int cp = idx & 63, jh = (idx >> 6) & 1, ig = (idx >> 7) & 3;
        int rr = 6 + (idx >> 9);
        int c0 = cp * 2;
        u32 a0 = cvt_pk_bf16(fd[it][0].x, fd[it][1].x);
        u32 a1 = cvt_pk_bf16(fd[it][2].x, fd[it][3].x);
        u32 b0 = cvt_pk_bf16(fd[it][0].y, fd[it][1].y);
        u32 b1 = cvt_pk_bf16(fd[it][2].y, fd[it][3].y);
        int didx = (c0 >> 4) * 64 + ig * 16 + (c0 & 15);
        *(uint2*)((char*)lds_x + rr * 8192 + didx * 16 + jh * 8) =
            make_uint2(a0, a1);
        *(uint2*)((char*)lds_x + rr * 8192 + (didx + 1) * 16 + jh * 8) =
            make_uint2(b0, b1);
    }

    // ---- Chunk0 coalesced epilogue: bounce slots 0..3 ----
    {
        float* bounce = (float*)lds_x;
        #pragma unroll
        for (int oh = 0; oh < 2; ++oh) {
            lds_barrier();   // all chunk0 LDS reads done; slot 6..9 writes in
            #pragma unroll
            for (int q = 0; q < 2; ++q)
                #pragma unroll
                for (int r = 0; r < 4; ++r) {
                    int o16  = (l >> 4) * 4 + r;
                    int col  = (nq * 2 + q) * 16 + (l & 15);
                    int col2 = (col + o16 * 4) & 127;
                    bounce[(o16 * 4 + row4) * 128 + col2] =
                        acc[oh][q][r] + blr[oh][r];
                }
            lds_barrier();
            const int ch = oh * 16 + wvid;
            #pragma unroll
            for (int k2 = 0; k2 < 2; ++k2) {
                int hrow = 2 * k2 + (l >> 5);
                int lcol = (l & 31) * 4;
                int pcol = (lcol + wvid * 4) & 127;
                f32x4 v = *(const f32x4*)&bounce[(wvid * 4 + hrow) * 128 + pcol];
                __builtin_nontemporal_store(
                    v, (f32x4*)&out[((size_t)(b * 32 + ch) * HH + (h0 + hrow)) *
                                    WW + lcol]);
            }
        }
    }

    // ================== Chunk 1: rows h0+4+row4, slots 4..9 ================
    // No extra barrier: epilogue barriers already ordered everything; chunk1
    // compute overlaps chunk0's nontemporal store drain.
    #pragma unroll
    for (int oh = 0; oh < 2; ++oh)
        #pragma unroll
        for (int q = 0; q < 2; ++q) acc[oh][q] = (f32x4){0.f, 0.f, 0.f, 0.f};

    #pragma unroll
    for (int lc = 0; lc < 3; ++lc) {
        #pragma unroll
        for (int k = 0; k < 3; ++k) {
            const bf16x8 a0 = af0[k * 3 + lc];
            const bf16x8 a1 = lds_w[(k * 3 + lc) * 128 + 64 + awb];
            const int s = 4 + row4 + k;
            #pragma unroll
            for (int q = 0; q < 2; ++q) {
                int t = (bb[lc] + (nq * 2 + q) * 64) & 511;
                bf16x8 bfv = lds_x[s * 512 + t];
                acc[0][q] = __builtin_amdgcn_mfma_f32_16x16x32_bf16(
                    a0, bfv, acc[0][q], 0, 0, 0);
                acc[1][q] = __builtin_amdgcn_mfma_f32_16x16x32_bf16(
                    a1, bfv, acc[1][q], 0, 0, 0);
            }
        }
    }

    // ---- Chunk1 coalesced epilogue: bounce slots 4..7 ----
    {
        float* bounce = (float*)((char*)lds_x + 4 * 8192);
        #pragma unroll
        for (int oh = 0; oh < 2; ++oh) {
            lds_barrier();   // all chunk1 LDS reads done
            #pragma unroll
            for (int q = 0; q < 2; ++q)
                #pragma unroll
                for (int r = 0; r < 4; ++r) {
                    int o16  = (l >> 4) * 4 + r;
                    int col  = (nq * 2 + q) * 16 + (l & 15);
                    int col2 = (col + o16 * 4) & 127;
                    bounce[(o16 * 4 + row4) * 128 + col2] =
                        acc[oh][q][r] + blr[oh][r];
                }
            lds_barrier();
            const int ch = oh * 16 + wvid;
            #pragma unroll
            for (int k2 = 0; k2 < 2; ++k2) {
                int hrow = 2 * k2 + (l >> 5);
                int lcol = (l & 31) * 4;
                int pcol = (lcol + wvid * 4) & 127;
                f32x4 v = *(const f32x4*)&bounce[(wvid * 4 + hrow) * 128 + pcol];
                __builtin_nontemporal_store(
                    v, (f32x4*)&out[((size_t)(b * 32 + ch) * HH +
                                     (h0 + 4 + hrow)) * WW + lcol]);
            }
        }
    }
}

extern "C" void kernel_launch(void* const* d_in, const int* in_sizes, int n_in,
                              void* d_out, int out_size, void* d_ws, size_t ws_size,
                              hipStream_t stream) {
    const float* x      = (const float*)d_in[0];
    const float* codes  = (const float*)d_in[1];
    const float* weight = (const float*)d_in[2];
    const float* A      = (const float*)d_in[3];
    const float* Bm     = (const float*)d_in[4];
    const float* bias   = (const float*)d_in[5];
    const float* bctx   = (const float*)d_in[6];
    float* out = (float*)d_out;

    hipLaunchKernelGGL(geps_mfma_kernel, dim3(256), dim3(1024), 0, stream,
                       x, codes, weight, A, Bm, bias, bctx, out);
}